// Round 1
// baseline (1136.675 us; speedup 1.0000x reference)
//
#include <hip/hip_runtime.h>
#include <cstdint>
#include <cstddef>

// Problem constants (fixed by the reference)
#define BB 64
#define KK 8
#define LL 256
#define VV 50257
#define DD 1024
#define EOS_TOK 50256
#define LNCf (-1000000000.0f)

// 4-byte-aligned float4 for loads/stores at stride V=50257 (odd) — rows of W /
// logits are not 16B aligned; let the compiler pick a legal wide-load form.
struct __attribute__((packed, aligned(4))) f4u { float x, y, z, w; };

// ---------------------------------------------------------------------------
// Kernel 1: logits[r][v] = dot(embed[token_r], W[:, v])   (fp32, tiled)
// grid = (M/64, ceil(V/128)), block = 256
// blockIdx.x = M-tile (fast-varying) so the 8 M-tiles of one N-tile run
// together and share the W panel through L2/L3.
// ---------------------------------------------------------------------------
__global__ __launch_bounds__(256) void gemm_logits(
    const float* __restrict__ embed, const float* __restrict__ W,
    const int* __restrict__ input_ids, const int* __restrict__ rss,
    const int* __restrict__ step_p, float* __restrict__ logits)
{
    __shared__ float As[16][64];    // [dk][m]
    __shared__ float Bs[16][128];   // [dk][n]

    const int tid = threadIdx.x;
    const int m0 = blockIdx.x * 64;
    const int n0 = blockIdx.y * 128;
    const int step = *step_p;

    // A gather: token for row (running_sequences[:,:,step-1]; pos0 = input_ids)
    const int am = tid >> 2;             // 0..63 row within tile
    const int ad = (tid & 3) << 2;       // 0,4,8,12 d-offset
    const int grow = m0 + am;
    const int tok = (step == 1) ? input_ids[grow] : rss[grow * LL + (step - 1)];
    const float* arow = embed + (size_t)tok * DD;

    const int ty = tid >> 5;             // 0..7  -> rows ty*8 .. ty*8+7
    const int tx = tid & 31;             // 0..31 -> cols tx*4 .. tx*4+3

    float acc[8][4];
#pragma unroll
    for (int i = 0; i < 8; ++i)
#pragma unroll
        for (int j = 0; j < 4; ++j) acc[i][j] = 0.f;

    for (int k0 = 0; k0 < DD; k0 += 16) {
        // stage A (embed rows are 16B aligned: tok*1024 floats)
        float4 av = *(const float4*)(arow + k0 + ad);
        As[ad + 0][am] = av.x; As[ad + 1][am] = av.y;
        As[ad + 2][am] = av.z; As[ad + 3][am] = av.w;
        // stage B: 16 x 128 floats, 2 x float4 per thread (stride-V rows: f4u)
#pragma unroll
        for (int i = 0; i < 2; ++i) {
            int idx = tid + i * 256;
            int d = idx >> 5;
            int c = (idx & 31) << 2;
            int col = n0 + c;
            const float* wp = W + (size_t)(k0 + d) * VV + col;
            float4 bv;
            if (col + 3 < VV) {
                f4u u = *(const f4u*)wp;
                bv.x = u.x; bv.y = u.y; bv.z = u.z; bv.w = u.w;
            } else {
                bv.x = (col + 0 < VV) ? wp[0] : 0.f;
                bv.y = (col + 1 < VV) ? wp[1] : 0.f;
                bv.z = (col + 2 < VV) ? wp[2] : 0.f;
                bv.w = (col + 3 < VV) ? wp[3] : 0.f;
            }
            *(float4*)&Bs[d][c] = bv;
        }
        __syncthreads();
#pragma unroll
        for (int dk = 0; dk < 16; ++dk) {
            float4 b4 = *(const float4*)&Bs[dk][tx << 2];
            float4 a0 = *(const float4*)&As[dk][ty << 3];
            float4 a1 = *(const float4*)&As[dk][(ty << 3) + 4];
            float a[8] = {a0.x, a0.y, a0.z, a0.w, a1.x, a1.y, a1.z, a1.w};
            float bbv[4] = {b4.x, b4.y, b4.z, b4.w};
#pragma unroll
            for (int i = 0; i < 8; ++i)
#pragma unroll
                for (int j = 0; j < 4; ++j) acc[i][j] += a[i] * bbv[j];
        }
        __syncthreads();
    }

#pragma unroll
    for (int i = 0; i < 8; ++i) {
        int r = m0 + (ty << 3) + i;
        int col = n0 + (tx << 2);
        float* op = logits + (size_t)r * VV + col;
        if (col + 3 < VV) {
            f4u u; u.x = acc[i][0]; u.y = acc[i][1]; u.z = acc[i][2]; u.w = acc[i][3];
            *(f4u*)op = u;
        } else {
#pragma unroll
            for (int j = 0; j < 4; ++j) if (col + j < VV) op[j] = acc[i][j];
        }
    }
}

// ---------------------------------------------------------------------------
// Kernel 2: per row r (512): lse[r] = logsumexp(logits[r]),
//           top-16 (value,index) of logits[r] sorted desc, ties -> lower index.
// grid = 512, block = 256
// ---------------------------------------------------------------------------
__global__ __launch_bounds__(256) void row_softmax_top16(
    const float* __restrict__ logits, float* __restrict__ lse_out,
    float* __restrict__ tv_out, int* __restrict__ ti_out)
{
    const int r = blockIdx.x;
    const int tid = threadIdx.x;
    const float* rowp = logits + (size_t)r * VV;

    float m = -INFINITY, s = 0.f;
    float v[16]; int id[16];
#pragma unroll
    for (int j = 0; j < 16; ++j) { v[j] = -INFINITY; id[j] = 0x7fffffff; }

    for (int c = tid; c < VV; c += 256) {
        float x = rowp[c];
        float mn = fmaxf(m, x);
        s = s * __expf(m - mn) + __expf(x - mn);
        m = mn;
        if (x > v[15]) {                 // strict: earlier (lower) index wins ties
            float cv = x; int ci = c;
#pragma unroll
            for (int j = 0; j < 16; ++j) {
                bool sw = (cv > v[j]);
                float tf = v[j]; int tii = id[j];
                if (sw) { v[j] = cv; id[j] = ci; cv = tf; ci = tii; }
            }
        }
    }

    // block logsumexp
    __shared__ float sm[256], ss[256];
    sm[tid] = m; ss[tid] = s;
    __syncthreads();
    for (int st = 128; st > 0; st >>= 1) {
        if (tid < st) {
            float m2 = sm[tid + st], s2 = ss[tid + st];
            float mm = fmaxf(sm[tid], m2);
            ss[tid] = ss[tid] * __expf(sm[tid] - mm) + s2 * __expf(m2 - mm);
            sm[tid] = mm;
        }
        __syncthreads();
    }
    if (tid == 0) lse_out[r] = sm[0] + logf(ss[0]);

    // block top-16 merge: pointer-walk over each thread's sorted list
    __shared__ float tv[256][17]; __shared__ int tis[256][17];   // +1 pad: no bank conflict
    __shared__ float redv[256];  __shared__ int redi[256];
#pragma unroll
    for (int j = 0; j < 16; ++j) { tv[tid][j] = v[j]; tis[tid][j] = id[j]; }
    int ptr = 0;
    __syncthreads();
    for (int rs = 0; rs < 16; ++rs) {
        float cv = (ptr < 16) ? tv[tid][ptr] : -INFINITY;
        int   ci = (ptr < 16) ? tis[tid][ptr] : 0x7fffffff;
        redv[tid] = cv; redi[tid] = ci;
        __syncthreads();
        for (int st = 128; st > 0; st >>= 1) {
            if (tid < st) {
                float v2 = redv[tid + st]; int i2 = redi[tid + st];
                if (v2 > redv[tid] || (v2 == redv[tid] && i2 < redi[tid])) {
                    redv[tid] = v2; redi[tid] = i2;
                }
            }
            __syncthreads();
        }
        float wv = redv[0]; int wi = redi[0];
        if (tid == 0) { tv_out[r * 16 + rs] = wv; ti_out[r * 16 + rs] = wi; }
        __syncthreads();                 // protect redv[0]/redi[0] reads
        if (ci == wi) ptr++;             // index unique within a row -> unique claim
    }
}

// ---------------------------------------------------------------------------
// Kernel 3: per batch b (64 blocks): merge 8x16 candidates -> top-16,
//           then the full beam bookkeeping; writes generated row + log probs.
// ---------------------------------------------------------------------------
__global__ __launch_bounds__(256) void beam_logic(
    const float* __restrict__ lse, const float* __restrict__ tv_in,
    const int* __restrict__ ti_in, const int* __restrict__ input_ids,
    const int* __restrict__ seq_state, const int* __restrict__ rss,
    const float* __restrict__ lps, const float* __restrict__ rlps,
    const int* __restrict__ isfin, const int* __restrict__ step_p,
    float* __restrict__ out, int* __restrict__ improve_ws)
{
    const int b = blockIdx.x;
    const int tid = threadIdx.x;

    __shared__ float redv[256]; __shared__ int redi[256];
    __shared__ float topv[16]; __shared__ int topflat[16];
    __shared__ float s_nlp[8], s_nrlp[8];
    __shared__ int s_mode, s_beam, s_sel_k, s_sel_v, s_step;

    // candidate per thread (128 candidates = 8 beams x row-top-16)
    float cv = -INFINITY; int ci = 0x7fffffff;
    if (tid < 128) {
        int k = tid >> 4, slot = tid & 15;
        int r = b * KK + k;
        cv = tv_in[r * 16 + slot] - lse[r] + rlps[b * KK + k];
        ci = k * VV + ti_in[r * 16 + slot];
    }
    // 16 rounds of block argmax (value desc, flat index asc on ties)
    for (int rs = 0; rs < 16; ++rs) {
        redv[tid] = cv; redi[tid] = ci;
        __syncthreads();
        for (int st = 128; st > 0; st >>= 1) {
            if (tid < st) {
                float v2 = redv[tid + st]; int i2 = redi[tid + st];
                if (v2 > redv[tid] || (v2 == redv[tid] && i2 < redi[tid])) {
                    redv[tid] = v2; redi[tid] = i2;
                }
            }
            __syncthreads();
        }
        float wv = redv[0]; int wi = redi[0];
        if (tid == 0) { topv[rs] = wv; topflat[rs] = wi; }
        __syncthreads();
        if (ci == wi) { cv = -INFINITY; ci = 0x7fffffff; }
    }

    if (tid == 0) {
        const int step = *step_p;
        s_step = step;
        const float stepf = (float)step;
        int tkk[16], tkid[16]; bool fin[16];
        float runtl[16], pen[16];
        for (int j = 0; j < 16; ++j) {
            int flat = topflat[j];
            tkk[j] = flat / VV; tkid[j] = flat % VV;
            fin[j] = (tkid[j] == EOS_TOK);
            runtl[j] = topv[j] + (fin[j] ? LNCf : 0.f);                  // running_topk
            pen[j]   = topv[j] / stepf + (fin[j] ? 0.f : LNCf);          // penalized
        }
        // next_topk_indices: top-8 of runtl (stable: strict >, scan ascending)
        int ni[8]; unsigned used = 0;
        for (int i = 0; i < 8; ++i) {
            int best = -1;
            for (int j = 0; j < 16; ++j)
                if (!((used >> j) & 1) && (best < 0 || runtl[j] > runtl[best])) best = j;
            ni[i] = best; used |= 1u << best;
            s_nrlp[i] = runtl[best];
        }
        // merged top-8 of [log_probs_state (8) ++ pen (16)]
        float merged[24];
        for (int j = 0; j < 8; ++j)  merged[j] = lps[b * KK + j];
        for (int j = 0; j < 16; ++j) merged[8 + j] = pen[j];
        int mi[8]; unsigned used2 = 0; bool anyf = false;
        for (int i = 0; i < 8; ++i) {
            int best = -1;
            for (int j = 0; j < 24; ++j)
                if (!((used2 >> j) & 1) && (best < 0 || merged[j] > merged[best])) best = j;
            mi[i] = best; used2 |= 1u << best;
            s_nlp[i] = merged[best];
            bool f = (best < 8) ? (isfin[b * KK + best] != 0) : fin[best - 8];
            anyf |= f;
        }
        // done-condition partials
        float worst = LNCf;
        if (anyf) {
            worst = lps[b * KK];
            for (int j = 1; j < 8; ++j) worst = fminf(worst, lps[b * KK + j]);
        }
        improve_ws[b] = ((rlps[b * KK] / stepf) > worst) ? 1 : 0;
        // which sequence feeds generated_tokens[b]
        if (anyf) {
            int m0i = mi[0];
            if (m0i < 8) { s_mode = 0; s_beam = m0i; }
            else { s_mode = 1; s_sel_k = tkk[m0i - 8]; s_sel_v = tkid[m0i - 8]; }
        } else {
            int j0 = ni[0];
            s_mode = 1; s_sel_k = tkk[j0]; s_sel_v = tkid[j0];
        }
    }
    __syncthreads();

    if (tid < LL) {
        int tokv;
        if (s_mode == 0) {
            tokv = seq_state[(b * KK + s_beam) * LL + tid];
        } else {
            tokv = (tid == s_step) ? s_sel_v
                 : ((tid == 0) ? input_ids[b * KK + s_sel_k]
                               : rss[(b * KK + s_sel_k) * LL + tid]);
        }
        out[b * LL + tid] = (float)tokv;
    }
    if (tid < 8) {
        out[BB * LL + 1 + b * KK + tid] = s_nlp[tid];
        out[BB * LL + 1 + BB * KK + b * KK + tid] = s_nrlp[tid];
    }
}

// ---------------------------------------------------------------------------
// Kernel 4: done = !(step < L && any_b(improvement_b))   (still_open == true)
// ---------------------------------------------------------------------------
__global__ __launch_bounds__(64) void finalize_done(
    const int* __restrict__ improve_ws, const int* __restrict__ step_p,
    float* __restrict__ out)
{
    int tid = threadIdx.x;                  // 64 threads = 1 wave
    bool imp = improve_ws[tid] != 0;
    bool any = __any(imp);
    if (tid == 0) {
        int step = *step_p;
        bool cont = (step < LL) && any;
        out[BB * LL] = cont ? 0.f : 1.f;
    }
}

// ---------------------------------------------------------------------------
extern "C" void kernel_launch(void* const* d_in, const int* in_sizes, int n_in,
                              void* d_out, int out_size, void* d_ws, size_t ws_size,
                              hipStream_t stream) {
    const int*   input_ids = (const int*)d_in[0];
    const int*   seq_state = (const int*)d_in[1];
    const int*   rss       = (const int*)d_in[2];
    const float* lps       = (const float*)d_in[3];
    const float* rlps      = (const float*)d_in[4];
    const int*   isfin     = (const int*)d_in[5];
    const float* embed     = (const float*)d_in[6];
    const float* W         = (const float*)d_in[7];
    const int*   step_p    = (const int*)d_in[8];
    float* out = (float*)d_out;

    // ws layout (needs ~103 MB): logits | lse | top16 vals | top16 idx | improve
    char* ws = (char*)d_ws;
    size_t off = 0;
    float* logits = (float*)(ws + off); off += (size_t)(BB * KK) * VV * sizeof(float);
    float* lse    = (float*)(ws + off); off += 512 * sizeof(float);
    float* tvals  = (float*)(ws + off); off += 512 * 16 * sizeof(float);
    int*   tidx   = (int*)(ws + off);   off += 512 * 16 * sizeof(int);
    int*   improw = (int*)(ws + off);   off += 64 * sizeof(int);
    (void)ws_size; (void)in_sizes; (void)n_in; (void)out_size;

    dim3 g1(512 / 64, (VV + 127) / 128);   // (8, 393)
    gemm_logits<<<g1, 256, 0, stream>>>(embed, W, input_ids, rss, step_p, logits);
    row_softmax_top16<<<512, 256, 0, stream>>>(logits, lse, tvals, tidx);
    beam_logic<<<64, 256, 0, stream>>>(lse, tvals, tidx, input_ids, seq_state,
                                       rss, lps, rlps, isfin, step_p, out, improw);
    finalize_done<<<1, 64, 0, stream>>>(improw, step_p, out);
}

// Round 2
// 490.455 us; speedup vs baseline: 2.3176x; 2.3176x over previous
//
#include <hip/hip_runtime.h>
#include <cstdint>
#include <cstddef>

// Problem constants (fixed by the reference)
#define BB 64
#define KK 8
#define LL 256
#define VV 50257
#define DD 1024
#define EOS_TOK 50256
#define LNCf (-1000000000.0f)

typedef unsigned short ushort_t;
typedef __attribute__((ext_vector_type(4))) float f32x4;
typedef __attribute__((ext_vector_type(8))) short bf16x8;

// 4-byte-aligned float4 for loads at stride V=50257 (odd): rows not 16B aligned.
struct __attribute__((packed, aligned(4))) f4u { float x, y, z, w; };

// round-to-nearest-even f32 -> bf16 bits (low 16)
__device__ inline unsigned bf16_rne(float x) {
    unsigned u = __float_as_uint(x);
    return (u + 0x7fffu + ((u >> 16) & 1u)) >> 16;
}
__device__ inline float bf16_back(unsigned b) { return __uint_as_float(b << 16); }

// ---------------------------------------------------------------------------
// Kernel 1: logits[512][V] = gathered_embed[512][1024] @ W[1024][V]
// Split-bf16 MFMA: x = hi + lo (bf16 RNE), A*B ~= Ahi*Bhi + Ahi*Blo + Alo*Bhi.
// BM=256, BN=128, BK=32; 512 threads = 8 waves (4m x 2n), wave tile 64x64.
// Reg-staged prefetch: issue next K-slice global loads before MFMA phase.
// LDS rows padded to 40 shorts (80 B = 5*16B): b128-aligned, ~2-way banks.
// Grid swizzle: both M-tiles of an N-column share an XCD (W panel in its L2).
// ---------------------------------------------------------------------------
__global__ __launch_bounds__(512) void gemm_logits(
    const float* __restrict__ embed, const float* __restrict__ W,
    const int* __restrict__ input_ids, const int* __restrict__ rss,
    const int* __restrict__ step_p, float* __restrict__ logits)
{
    __shared__ ushort_t Ahi[256][40], Alo[256][40];   // 20 KB + 20 KB
    __shared__ ushort_t Bhi[128][40], Blo[128][40];   // 10 KB + 10 KB  (60 KB total)

    const int tid = threadIdx.x;
    const int g = blockIdx.x;
    int n_t, m_t;
    if (g >= 784) { n_t = 392; m_t = g - 784; }
    else { n_t = (g & 7) + 8 * (g >> 4); m_t = (g >> 3) & 1; }
    const int m0 = m_t * 256;
    const int n0 = n_t * 128;
    const int step = *step_p;

    // ---- A staging: thread t -> row t>>1, k-offset (t&1)*16 (16 floats) ----
    const int row_a = tid >> 1;
    const int ka = (tid & 1) << 4;
    const int grow = m0 + row_a;
    const int tok = (step == 1) ? input_ids[grow] : rss[grow * LL + (step - 1)];
    const float* arow = embed + (size_t)tok * DD + ka;

    // ---- B staging: thread t -> W row dk=t>>4, cols cb=t&15 + 16*i --------
    const int dk_b = tid >> 4;
    const int cb = tid & 15;
    const float* wrow0 = W + (size_t)dk_b * VV + n0 + cb;
    bool bval[8];
#pragma unroll
    for (int i = 0; i < 8; ++i) bval[i] = (n0 + cb + 16 * i) < VV;

    float af[16];
    float bf[8];

    auto load_tile = [&](int k0) {
#pragma unroll
        for (int i = 0; i < 4; ++i) {
            float4 v = *(const float4*)(arow + k0 + 4 * i);
            af[4 * i + 0] = v.x; af[4 * i + 1] = v.y;
            af[4 * i + 2] = v.z; af[4 * i + 3] = v.w;
        }
        const float* wp = wrow0 + (size_t)k0 * VV;
#pragma unroll
        for (int i = 0; i < 8; ++i) bf[i] = bval[i] ? wp[16 * i] : 0.f;
    };

    auto store_tile = [&]() {
        unsigned hi[16], lo[16];
#pragma unroll
        for (int i = 0; i < 16; ++i) {
            unsigned h = bf16_rne(af[i]);
            float r = af[i] - bf16_back(h);
            hi[i] = h; lo[i] = bf16_rne(r);
        }
        uint4 u;
        u.x = hi[0] | (hi[1] << 16);  u.y = hi[2] | (hi[3] << 16);
        u.z = hi[4] | (hi[5] << 16);  u.w = hi[6] | (hi[7] << 16);
        *(uint4*)&Ahi[row_a][ka] = u;
        u.x = hi[8] | (hi[9] << 16);  u.y = hi[10] | (hi[11] << 16);
        u.z = hi[12] | (hi[13] << 16); u.w = hi[14] | (hi[15] << 16);
        *(uint4*)&Ahi[row_a][ka + 8] = u;
        u.x = lo[0] | (lo[1] << 16);  u.y = lo[2] | (lo[3] << 16);
        u.z = lo[4] | (lo[5] << 16);  u.w = lo[6] | (lo[7] << 16);
        *(uint4*)&Alo[row_a][ka] = u;
        u.x = lo[8] | (lo[9] << 16);  u.y = lo[10] | (lo[11] << 16);
        u.z = lo[12] | (lo[13] << 16); u.w = lo[14] | (lo[15] << 16);
        *(uint4*)&Alo[row_a][ka + 8] = u;
#pragma unroll
        for (int i = 0; i < 8; ++i) {
            unsigned h = bf16_rne(bf[i]);
            float r = bf[i] - bf16_back(h);
            Bhi[cb + 16 * i][dk_b] = (ushort_t)h;
            Blo[cb + 16 * i][dk_b] = (ushort_t)bf16_rne(r);
        }
    };

    // ---- MFMA geometry ----
    const int wave = tid >> 6;
    const int lane = tid & 63;
    const int wm = wave >> 1;         // 0..3
    const int wn = wave & 1;          // 0..1
    const int fr = lane & 15;
    const int kb = (lane >> 4) << 3;  // k-base in shorts: 0,8,16,24

    f32x4 acc[4][4];
#pragma unroll
    for (int fm = 0; fm < 4; ++fm)
#pragma unroll
        for (int fn = 0; fn < 4; ++fn)
#pragma unroll
            for (int e = 0; e < 4; ++e) acc[fm][fn][e] = 0.f;

    auto compute = [&]() {
        bf16x8 bh[4], bl[4];
#pragma unroll
        for (int fn = 0; fn < 4; ++fn) {
            bh[fn] = *(const bf16x8*)&Bhi[wn * 64 + fn * 16 + fr][kb];
            bl[fn] = *(const bf16x8*)&Blo[wn * 64 + fn * 16 + fr][kb];
        }
#pragma unroll
        for (int fm = 0; fm < 4; ++fm) {
            bf16x8 ah = *(const bf16x8*)&Ahi[wm * 64 + fm * 16 + fr][kb];
            bf16x8 al = *(const bf16x8*)&Alo[wm * 64 + fm * 16 + fr][kb];
#pragma unroll
            for (int fn = 0; fn < 4; ++fn) {
                acc[fm][fn] = __builtin_amdgcn_mfma_f32_16x16x32_bf16(ah, bh[fn], acc[fm][fn], 0, 0, 0);
                acc[fm][fn] = __builtin_amdgcn_mfma_f32_16x16x32_bf16(ah, bl[fn], acc[fm][fn], 0, 0, 0);
                acc[fm][fn] = __builtin_amdgcn_mfma_f32_16x16x32_bf16(al, bh[fn], acc[fm][fn], 0, 0, 0);
            }
        }
    };

    load_tile(0);
    store_tile();
    __syncthreads();
    for (int t = 0; t < 31; ++t) {
        load_tile((t + 1) * 32);   // prefetch next slice (hides under MFMA)
        compute();                 // consume LDS tile t
        __syncthreads();
        store_tile();              // vmcnt drain + convert + LDS write (t+1)
        __syncthreads();
    }
    compute();

    // ---- epilogue: C/D layout col=lane&15, row=(lane>>4)*4+reg ----
    const int crow0 = m0 + wm * 64 + (lane >> 4) * 4;
    const int ccol0 = n0 + wn * 64 + (lane & 15);
#pragma unroll
    for (int fm = 0; fm < 4; ++fm)
#pragma unroll
        for (int fn = 0; fn < 4; ++fn) {
            int col = ccol0 + fn * 16;
            if (col < VV) {
#pragma unroll
                for (int r = 0; r < 4; ++r)
                    logits[(size_t)(crow0 + fm * 16 + r) * VV + col] = acc[fm][fn][r];
            }
        }
}

// ---------------------------------------------------------------------------
// Kernel 2: per row r (512): lse[r] = logsumexp(logits[r]); top-16 desc,
// ties -> lower index. float4 loads, 8-level pairwise sorted-merge.
// ---------------------------------------------------------------------------
__global__ __launch_bounds__(256) void row_softmax_top16(
    const float* __restrict__ logits, float* __restrict__ lse_out,
    float* __restrict__ tv_out, int* __restrict__ ti_out)
{
    const int r = blockIdx.x;
    const int tid = threadIdx.x;
    const float* rowp = logits + (size_t)r * VV;

    float m = -INFINITY, s = 0.f;
    float v[16]; int id[16];
#pragma unroll
    for (int j = 0; j < 16; ++j) { v[j] = -INFINITY; id[j] = 0x7fffffff; }

    auto ins = [&](float x, int c) {
        if (x > v[15]) {
            float cv = x; int ci = c;
#pragma unroll
            for (int j = 0; j < 16; ++j) {
                bool sw = (cv > v[j]);
                float tf = v[j]; int ti2 = id[j];
                if (sw) { v[j] = cv; id[j] = ci; cv = tf; ci = ti2; }
            }
        }
    };

    for (int i = 0; i < 49; ++i) {           // 49*1024 = 50176 elems
        int c = i * 1024 + tid * 4;
        f4u x4 = *(const f4u*)(rowp + c);
        float m4 = fmaxf(fmaxf(x4.x, x4.y), fmaxf(x4.z, x4.w));
        float mn = fmaxf(m, m4);
        s = s * __expf(m - mn) + __expf(x4.x - mn) + __expf(x4.y - mn)
            + __expf(x4.z - mn) + __expf(x4.w - mn);
        m = mn;
        if (m4 > v[15]) { ins(x4.x, c); ins(x4.y, c + 1); ins(x4.z, c + 2); ins(x4.w, c + 3); }
    }
    {   // tail 50176..50256 (81 elems)
        int c = 50176 + tid;
        if (c < VV) {
            float x = rowp[c];
            float mn = fmaxf(m, x);
            s = s * __expf(m - mn) + __expf(x - mn);
            m = mn;
            ins(x, c);
        }
    }

    // block logsumexp
    __shared__ float sm[256], ss[256];
    sm[tid] = m; ss[tid] = s;
    __syncthreads();
    for (int st = 128; st > 0; st >>= 1) {
        if (tid < st) {
            float m2 = sm[tid + st], s2 = ss[tid + st];
            float mm = fmaxf(sm[tid], m2);
            ss[tid] = ss[tid] * __expf(sm[tid] - mm) + s2 * __expf(m2 - mm);
            sm[tid] = mm;
        }
        __syncthreads();
    }
    if (tid == 0) lse_out[r] = sm[0] + logf(ss[0]);

    // pairwise sorted-merge tree (8 levels); 2-pointer merge via LDS reads
    __shared__ float mv[256][17];
    __shared__ int mi[256][17];
#pragma unroll
    for (int j = 0; j < 16; ++j) { mv[tid][j] = v[j]; mi[tid][j] = id[j]; }
    __syncthreads();
    for (int st = 128; st >= 1; st >>= 1) {
        float nv[16]; int ni[16];
        if (tid < st) {
            const float* av = mv[tid];      const int* ai = mi[tid];
            const float* bv = mv[tid + st]; const int* bi = mi[tid + st];
            int pa = 0, pb = 0;
#pragma unroll
            for (int o = 0; o < 16; ++o) {
                float va = av[pa], vb = bv[pb];
                int ia = ai[pa], ib = bi[pb];
                bool ta = (va > vb) || (va == vb && ia < ib);
                nv[o] = ta ? va : vb;
                ni[o] = ta ? ia : ib;
                pa += ta ? 1 : 0;
                pb += ta ? 0 : 1;
            }
        }
        __syncthreads();
        if (tid < st) {
#pragma unroll
            for (int j = 0; j < 16; ++j) { mv[tid][j] = nv[j]; mi[tid][j] = ni[j]; }
        }
        __syncthreads();
    }
    if (tid < 16) {
        tv_out[r * 16 + tid] = mv[0][tid];
        ti_out[r * 16 + tid] = mi[0][tid];
    }
}

// ---------------------------------------------------------------------------
// Kernel 3: per batch b: merge 8x16 candidates -> top-16, beam bookkeeping.
// ---------------------------------------------------------------------------
__global__ __launch_bounds__(256) void beam_logic(
    const float* __restrict__ lse, const float* __restrict__ tv_in,
    const int* __restrict__ ti_in, const int* __restrict__ input_ids,
    const int* __restrict__ seq_state, const int* __restrict__ rss,
    const float* __restrict__ lps, const float* __restrict__ rlps,
    const int* __restrict__ isfin, const int* __restrict__ step_p,
    float* __restrict__ out, int* __restrict__ improve_ws)
{
    const int b = blockIdx.x;
    const int tid = threadIdx.x;

    __shared__ float redv[256]; __shared__ int redi[256];
    __shared__ float topv[16]; __shared__ int topflat[16];
    __shared__ float s_nlp[8], s_nrlp[8];
    __shared__ int s_mode, s_beam, s_sel_k, s_sel_v, s_step;

    float cv = -INFINITY; int ci = 0x7fffffff;
    if (tid < 128) {
        int k = tid >> 4, slot = tid & 15;
        int r = b * KK + k;
        cv = tv_in[r * 16 + slot] - lse[r] + rlps[b * KK + k];
        ci = k * VV + ti_in[r * 16 + slot];
    }
    for (int rs = 0; rs < 16; ++rs) {
        redv[tid] = cv; redi[tid] = ci;
        __syncthreads();
        for (int st = 128; st > 0; st >>= 1) {
            if (tid < st) {
                float v2 = redv[tid + st]; int i2 = redi[tid + st];
                if (v2 > redv[tid] || (v2 == redv[tid] && i2 < redi[tid])) {
                    redv[tid] = v2; redi[tid] = i2;
                }
            }
            __syncthreads();
        }
        float wv = redv[0]; int wi = redi[0];
        if (tid == 0) { topv[rs] = wv; topflat[rs] = wi; }
        __syncthreads();
        if (ci == wi) { cv = -INFINITY; ci = 0x7fffffff; }
    }

    if (tid == 0) {
        const int step = *step_p;
        s_step = step;
        const float stepf = (float)step;
        int tkk[16], tkid[16]; bool fin[16];
        float runtl[16], pen[16];
        for (int j = 0; j < 16; ++j) {
            int flat = topflat[j];
            tkk[j] = flat / VV; tkid[j] = flat % VV;
            fin[j] = (tkid[j] == EOS_TOK);
            runtl[j] = topv[j] + (fin[j] ? LNCf : 0.f);
            pen[j]   = topv[j] / stepf + (fin[j] ? 0.f : LNCf);
        }
        int ni[8]; unsigned used = 0;
        for (int i = 0; i < 8; ++i) {
            int best = -1;
            for (int j = 0; j < 16; ++j)
                if (!((used >> j) & 1) && (best < 0 || runtl[j] > runtl[best])) best = j;
            ni[i] = best; used |= 1u << best;
            s_nrlp[i] = runtl[best];
        }
        float merged[24];
        for (int j = 0; j < 8; ++j)  merged[j] = lps[b * KK + j];
        for (int j = 0; j < 16; ++j) merged[8 + j] = pen[j];
        int mi2[8]; unsigned used2 = 0; bool anyf = false;
        for (int i = 0; i < 8; ++i) {
            int best = -1;
            for (int j = 0; j < 24; ++j)
                if (!((used2 >> j) & 1) && (best < 0 || merged[j] > merged[best])) best = j;
            mi2[i] = best; used2 |= 1u << best;
            s_nlp[i] = merged[best];
            bool f = (best < 8) ? (isfin[b * KK + best] != 0) : fin[best - 8];
            anyf |= f;
        }
        float worst = LNCf;
        if (anyf) {
            worst = lps[b * KK];
            for (int j = 1; j < 8; ++j) worst = fminf(worst, lps[b * KK + j]);
        }
        improve_ws[b] = ((rlps[b * KK] / stepf) > worst) ? 1 : 0;
        if (anyf) {
            int m0i = mi2[0];
            if (m0i < 8) { s_mode = 0; s_beam = m0i; }
            else { s_mode = 1; s_sel_k = tkk[m0i - 8]; s_sel_v = tkid[m0i - 8]; }
        } else {
            int j0 = ni[0];
            s_mode = 1; s_sel_k = tkk[j0]; s_sel_v = tkid[j0];
        }
    }
    __syncthreads();

    if (tid < LL) {
        int tokv;
        if (s_mode == 0) {
            tokv = seq_state[(b * KK + s_beam) * LL + tid];
        } else {
            tokv = (tid == s_step) ? s_sel_v
                 : ((tid == 0) ? input_ids[b * KK + s_sel_k]
                               : rss[(b * KK + s_sel_k) * LL + tid]);
        }
        out[b * LL + tid] = (float)tokv;
    }
    if (tid < 8) {
        out[BB * LL + 1 + b * KK + tid] = s_nlp[tid];
        out[BB * LL + 1 + BB * KK + b * KK + tid] = s_nrlp[tid];
    }
}

// ---------------------------------------------------------------------------
__global__ __launch_bounds__(64) void finalize_done(
    const int* __restrict__ improve_ws, const int* __restrict__ step_p,
    float* __restrict__ out)
{
    int tid = threadIdx.x;
    bool imp = improve_ws[tid] != 0;
    bool any = __any(imp);
    if (tid == 0) {
        int step = *step_p;
        bool cont = (step < LL) && any;
        out[BB * LL] = cont ? 0.f : 1.f;
    }
}

// ---------------------------------------------------------------------------
extern "C" void kernel_launch(void* const* d_in, const int* in_sizes, int n_in,
                              void* d_out, int out_size, void* d_ws, size_t ws_size,
                              hipStream_t stream) {
    const int*   input_ids = (const int*)d_in[0];
    const int*   seq_state = (const int*)d_in[1];
    const int*   rss       = (const int*)d_in[2];
    const float* lps       = (const float*)d_in[3];
    const float* rlps      = (const float*)d_in[4];
    const int*   isfin     = (const int*)d_in[5];
    const float* embed     = (const float*)d_in[6];
    const float* W         = (const float*)d_in[7];
    const int*   step_p    = (const int*)d_in[8];
    float* out = (float*)d_out;

    char* ws = (char*)d_ws;
    size_t off = 0;
    float* logits = (float*)(ws + off); off += (size_t)(BB * KK) * VV * sizeof(float);
    float* lse    = (float*)(ws + off); off += 512 * sizeof(float);
    float* tvals  = (float*)(ws + off); off += 512 * 16 * sizeof(float);
    int*   tidx   = (int*)(ws + off);   off += 512 * 16 * sizeof(int);
    int*   improw = (int*)(ws + off);   off += 64 * sizeof(int);
    (void)ws_size; (void)in_sizes; (void)n_in; (void)out_size;

    gemm_logits<<<786, 512, 0, stream>>>(embed, W, input_ids, rss, step_p, logits);
    row_softmax_top16<<<512, 256, 0, stream>>>(logits, lse, tvals, tidx);
    beam_logic<<<64, 256, 0, stream>>>(lse, tvals, tidx, input_ids, seq_state,
                                       rss, lps, rlps, isfin, step_p, out, improw);
    finalize_done<<<1, 64, 0, stream>>>(improw, step_p, out);
}

// Round 3
// 431.948 us; speedup vs baseline: 2.6315x; 1.1355x over previous
//
#include <hip/hip_runtime.h>
#include <cstdint>
#include <cstddef>

// Problem constants (fixed by the reference)
#define BB 64
#define KK 8
#define LL 256
#define VV 50257
#define DD 1024
#define EOS_TOK 50256
#define LNCf (-1000000000.0f)
#define NSLICE 16768            // per-pass n-width = 131 tiles * 128 (3*16768 = 50304 >= VV)
#define NT_PASS 131

typedef unsigned short ushort_t;
typedef __attribute__((ext_vector_type(4))) float f32x4;
typedef __attribute__((ext_vector_type(8))) short bf16x8;

// 4-byte-aligned float4 for loads at stride V=50257 (odd): rows not 16B aligned.
struct __attribute__((packed, aligned(4))) f4u { float x, y, z, w; };

// round-to-nearest-even f32 -> bf16 bits
__device__ inline ushort_t bf16_rne(float x) {
    unsigned u = __float_as_uint(x);
    return (ushort_t)((u + 0x7fffu + ((u >> 16) & 1u)) >> 16);
}
__device__ inline float bf16_f32(ushort_t b) { return __uint_as_float(((unsigned)b) << 16); }

// ---------------------------------------------------------------------------
// conv_a: gather token rows, split fp32 embed -> bf16 hi + bf16 lo.
// grid 512 blocks x 256 threads; thread t handles 4 floats of its row.
// ---------------------------------------------------------------------------
__global__ __launch_bounds__(256) void conv_a(
    const float* __restrict__ embed, const int* __restrict__ input_ids,
    const int* __restrict__ rss, const int* __restrict__ step_p,
    ushort_t* __restrict__ At_hi, ushort_t* __restrict__ At_lo)
{
    const int r = blockIdx.x;
    const int t = threadIdx.x;
    const int step = *step_p;
    const int tok = (step == 1) ? input_ids[r] : rss[r * LL + (step - 1)];
    f32x4 v = *(const f32x4*)(embed + (size_t)tok * DD + t * 4);
    ushort4 h, l;
    h.x = bf16_rne(v[0]); l.x = bf16_rne(v[0] - bf16_f32(h.x));
    h.y = bf16_rne(v[1]); l.y = bf16_rne(v[1] - bf16_f32(h.y));
    h.z = bf16_rne(v[2]); l.z = bf16_rne(v[2] - bf16_f32(h.z));
    h.w = bf16_rne(v[3]); l.w = bf16_rne(v[3] - bf16_f32(h.w));
    *(ushort4*)(At_hi + (size_t)r * DD + t * 4) = h;
    *(ushort4*)(At_lo + (size_t)r * DD + t * 4) = l;
}

// ---------------------------------------------------------------------------
// conv_w: transpose+convert one n-slice of W: W[k][n] f32 -> Wt[n_local][k] bf16.
// grid (16 k-tiles, 262 n-tiles) x 256 threads, 64x64 tile via LDS.
// Cols >= VV write 0 (their logits = 0, excluded downstream by n_valid).
// ---------------------------------------------------------------------------
__global__ __launch_bounds__(256) void conv_w(
    const float* __restrict__ W, ushort_t* __restrict__ Wt, int nglob_base)
{
    __shared__ ushort_t tile[64][66];
    const int t = threadIdx.x;
    const int k0 = blockIdx.x * 64;
    const int nloc0 = blockIdx.y * 64;
    const int n0 = nglob_base + nloc0;
    const int kr = t >> 4;           // 0..15
    const int nc = (t & 15) * 4;     // 0..60
#pragma unroll
    for (int j = 0; j < 4; ++j) {
        const int k = k0 + kr + j * 16;
        const int n = n0 + nc;
        const float* wp = W + (size_t)k * VV + n;
        float a, b2, c, d;
        if (n + 3 < VV) { f4u u = *(const f4u*)wp; a = u.x; b2 = u.y; c = u.z; d = u.w; }
        else {
            a  = (n     < VV) ? wp[0] : 0.f;
            b2 = (n + 1 < VV) ? wp[1] : 0.f;
            c  = (n + 2 < VV) ? wp[2] : 0.f;
            d  = (n + 3 < VV) ? wp[3] : 0.f;
        }
        tile[kr + j * 16][nc + 0] = bf16_rne(a);
        tile[kr + j * 16][nc + 1] = bf16_rne(b2);
        tile[kr + j * 16][nc + 2] = bf16_rne(c);
        tile[kr + j * 16][nc + 3] = bf16_rne(d);
    }
    __syncthreads();
    const int nr = t >> 2;           // 0..63
    const int kc = (t & 3) * 16;     // 0,16,32,48
    ushort_t vals[16];
#pragma unroll
    for (int j = 0; j < 16; ++j) vals[j] = tile[kc + j][nr];
    uint4 u0, u1;
    u0.x = vals[0] | ((unsigned)vals[1] << 16);  u0.y = vals[2] | ((unsigned)vals[3] << 16);
    u0.z = vals[4] | ((unsigned)vals[5] << 16);  u0.w = vals[6] | ((unsigned)vals[7] << 16);
    u1.x = vals[8] | ((unsigned)vals[9] << 16);  u1.y = vals[10] | ((unsigned)vals[11] << 16);
    u1.z = vals[12] | ((unsigned)vals[13] << 16); u1.w = vals[14] | ((unsigned)vals[15] << 16);
    ushort_t* op = Wt + (size_t)(nloc0 + nr) * DD + k0 + kc;
    *(uint4*)op = u0;
    *(uint4*)(op + 8) = u1;
}

// ---------------------------------------------------------------------------
// gemm_pass: logits_slice[512][16768] f32 = (Ahi+Alo)[512][1024] @ Wt^T (bf16)
// 2-term split MFMA: acc += Ahi*B ; acc += Alo*B.
// BM=128, BN=128, BK=64; 256 threads = 4 waves (2m x 2n), wave tile 64x64.
// m97 structure: global_load_lds dwordx4 staging (chunk-XOR swizzled via
// per-lane source address), 2 barriers per K-step, swizzled ds_read_b128.
// ---------------------------------------------------------------------------
__global__ __launch_bounds__(256) void gemm_pass(
    const ushort_t* __restrict__ At_hi, const ushort_t* __restrict__ At_lo,
    const ushort_t* __restrict__ Wt, float* __restrict__ logits)
{
    __shared__ ushort_t smem[24576];          // 48 KB: Ahi | Alo | Bs (16 KB each)
    ushort_t* Ah = smem;
    ushort_t* Al = smem + 8192;
    ushort_t* Bs = smem + 16384;

    const int tid = threadIdx.x;
    const int wave = tid >> 6;
    const int lane = tid & 63;
    const int m_t = blockIdx.x & 3;
    const int n_t = blockIdx.x >> 2;          // 0..130
    const int m0 = m_t * 128;
    const int wm = wave >> 1, wn = wave & 1;
    const int fr = lane & 15;
    const int q  = lane >> 4;

    const int srow = lane >> 3;               // 0..7 (row within 8-row issue group)
    const int schunk = lane & 7;              // 0..7 (16B chunk within 128B row)

    f32x4 acc[4][4];
#pragma unroll
    for (int i = 0; i < 4; ++i)
#pragma unroll
        for (int j = 0; j < 4; ++j)
#pragma unroll
            for (int e = 0; e < 4; ++e) acc[i][j][e] = 0.f;

    for (int t7 = 0; t7 < 16; ++t7) {
        const int kb = t7 * 64;               // k offset in shorts
        // ---- stage: 12 x global_load_lds(16B) per thread-slot (4 Ahi, 4 Alo, 4 B)
#pragma unroll
        for (int i = 0; i < 4; ++i) {
            const int row = (i * 4 + wave) * 8 + srow;            // 0..127
            const int soff = (schunk ^ (row & 7)) * 8;            // swizzled chunk (shorts)
            const ushort_t* srcH = At_hi + (size_t)(m0 + row) * DD + kb + soff;
            const ushort_t* srcL = At_lo + (size_t)(m0 + row) * DD + kb + soff;
            const ushort_t* srcB = Wt + (size_t)(n_t * 128 + row) * DD + kb + soff;
            __builtin_amdgcn_global_load_lds(
                (const __attribute__((address_space(1))) unsigned int*)srcH,
                (__attribute__((address_space(3))) unsigned int*)(Ah + (i * 4 + wave) * 512),
                16, 0, 0);
            __builtin_amdgcn_global_load_lds(
                (const __attribute__((address_space(1))) unsigned int*)srcL,
                (__attribute__((address_space(3))) unsigned int*)(Al + (i * 4 + wave) * 512),
                16, 0, 0);
            __builtin_amdgcn_global_load_lds(
                (const __attribute__((address_space(1))) unsigned int*)srcB,
                (__attribute__((address_space(3))) unsigned int*)(Bs + (i * 4 + wave) * 512),
                16, 0, 0);
        }
        __syncthreads();                       // drains vmcnt: staged data visible
        // ---- compute: 2 k-halves x 4x4 fragments x {hi,lo} = 64 MFMA / wave
#pragma unroll
        for (int h = 0; h < 2; ++h) {
            bf16x8 b[4];
#pragma unroll
            for (int fn = 0; fn < 4; ++fn) {
                const int row = wn * 64 + fn * 16 + fr;
                const int off = ((h * 4 + q) ^ (row & 7)) * 16;
                b[fn] = *(const bf16x8*)((const char*)(Bs + row * 64) + off);
            }
#pragma unroll
            for (int fm = 0; fm < 4; ++fm) {
                const int row = wm * 64 + fm * 16 + fr;
                const int off = ((h * 4 + q) ^ (row & 7)) * 16;
                bf16x8 ah = *(const bf16x8*)((const char*)(Ah + row * 64) + off);
                bf16x8 al = *(const bf16x8*)((const char*)(Al + row * 64) + off);
#pragma unroll
                for (int fn = 0; fn < 4; ++fn) {
                    acc[fm][fn] = __builtin_amdgcn_mfma_f32_16x16x32_bf16(ah, b[fn], acc[fm][fn], 0, 0, 0);
                    acc[fm][fn] = __builtin_amdgcn_mfma_f32_16x16x32_bf16(al, b[fn], acc[fm][fn], 0, 0, 0);
                }
            }
        }
        __syncthreads();                       // protect LDS for next stage
    }

    // ---- epilogue: C/D layout col=lane&15, row=(lane>>4)*4+e; f32 direct store
    const int crow0 = m0 + wm * 64 + q * 4;
    const int ccol0 = n_t * 128 + wn * 64 + fr;
#pragma unroll
    for (int fm = 0; fm < 4; ++fm)
#pragma unroll
        for (int fn = 0; fn < 4; ++fn) {
            const int col = ccol0 + fn * 16;
#pragma unroll
            for (int e = 0; e < 4; ++e)
                logits[(size_t)(crow0 + fm * 16 + e) * NSLICE + col] = acc[fm][fn][e];
        }
}

// ---------------------------------------------------------------------------
// topk_partial: per row r (512): online (max, sumexp) + top-16 over one
// 16768-col f32 slice. Writes per-(row,pass) partials with GLOBAL indices.
// ---------------------------------------------------------------------------
__global__ __launch_bounds__(256) void topk_partial(
    const float* __restrict__ lslice, float* __restrict__ pms,
    float* __restrict__ ptv, int* __restrict__ pti,
    int pass, int n_valid)
{
    const int r = blockIdx.x;
    const int tid = threadIdx.x;
    const float* rowp = lslice + (size_t)r * NSLICE;
    const int gbase = pass * NSLICE;

    float m = -INFINITY, s = 0.f;
    float v[16]; int id[16];
#pragma unroll
    for (int j = 0; j < 16; ++j) { v[j] = -INFINITY; id[j] = 0x7fffffff; }

    auto ins = [&](float x, int c) {
        if (x > v[15]) {
            float cv = x; int ci = c;
#pragma unroll
            for (int j = 0; j < 16; ++j) {
                bool sw = (cv > v[j]);
                float tf = v[j]; int ti2 = id[j];
                if (sw) { v[j] = cv; id[j] = ci; cv = tf; ci = ti2; }
            }
        }
    };

    for (int i = 0; i < 17; ++i) {
        const int c4 = i * 256 + tid;
        if (c4 >= NSLICE / 4) break;
        const int col = c4 * 4;
        f32x4 x = *(const f32x4*)(rowp + col);
        if (col + 3 >= n_valid) {
            if (col + 0 >= n_valid) x[0] = -INFINITY;
            if (col + 1 >= n_valid) x[1] = -INFINITY;
            if (col + 2 >= n_valid) x[2] = -INFINITY;
            if (col + 3 >= n_valid) x[3] = -INFINITY;
        }
        const float m4 = fmaxf(fmaxf(x[0], x[1]), fmaxf(x[2], x[3]));
        const float mn = fmaxf(m, m4);
        s = s * __expf(m - mn) + __expf(x[0] - mn) + __expf(x[1] - mn)
            + __expf(x[2] - mn) + __expf(x[3] - mn);
        m = mn;
        if (m4 > v[15]) { ins(x[0], col); ins(x[1], col + 1); ins(x[2], col + 2); ins(x[3], col + 3); }
    }

    // block (m,s) reduce
    __shared__ float sm[256], ss[256];
    sm[tid] = m; ss[tid] = s;
    __syncthreads();
    for (int st = 128; st > 0; st >>= 1) {
        if (tid < st) {
            float m2 = sm[tid + st], s2 = ss[tid + st];
            float mm = fmaxf(sm[tid], m2);
            ss[tid] = ss[tid] * __expf(sm[tid] - mm) + s2 * __expf(m2 - mm);
            sm[tid] = mm;
        }
        __syncthreads();
    }
    if (tid == 0) { pms[(r * 3 + pass) * 2] = sm[0]; pms[(r * 3 + pass) * 2 + 1] = ss[0]; }

    // pairwise sorted-merge tree (8 levels)
    __shared__ float mv[256][17];
    __shared__ int mi[256][17];
#pragma unroll
    for (int j = 0; j < 16; ++j) { mv[tid][j] = v[j]; mi[tid][j] = id[j]; }
    __syncthreads();
    for (int st = 128; st >= 1; st >>= 1) {
        float nv[16]; int ni[16];
        if (tid < st) {
            const float* av = mv[tid];      const int* ai = mi[tid];
            const float* bv = mv[tid + st]; const int* bi = mi[tid + st];
            int pa = 0, pb = 0;
#pragma unroll
            for (int o = 0; o < 16; ++o) {
                float va = av[pa], vb = bv[pb];
                int ia = ai[pa], ib = bi[pb];
                bool ta = (va > vb) || (va == vb && ia < ib);
                nv[o] = ta ? va : vb;
                ni[o] = ta ? ia : ib;
                pa += ta ? 1 : 0;
                pb += ta ? 0 : 1;
            }
        }
        __syncthreads();
        if (tid < st) {
#pragma unroll
            for (int j = 0; j < 16; ++j) { mv[tid][j] = nv[j]; mi[tid][j] = ni[j]; }
        }
        __syncthreads();
    }
    if (tid < 16) {
        ptv[(r * 3 + pass) * 16 + tid] = mv[0][tid];
        pti[(r * 3 + pass) * 16 + tid] = (mi[0][tid] == 0x7fffffff) ? 0x7fffffff : gbase + mi[0][tid];
    }
}

// ---------------------------------------------------------------------------
// final_merge: per row: merge 3 (m,s) -> lse; 3-way merge sorted top-16 lists.
// ---------------------------------------------------------------------------
__global__ __launch_bounds__(64) void final_merge(
    const float* __restrict__ pms, const float* __restrict__ ptv,
    const int* __restrict__ pti, float* __restrict__ lse_out,
    float* __restrict__ tv_out, int* __restrict__ ti_out)
{
    const int r = blockIdx.x;
    if (threadIdx.x != 0) return;
    float M = -INFINITY;
    for (int p = 0; p < 3; ++p) M = fmaxf(M, pms[(r * 3 + p) * 2]);
    float S = 0.f;
    for (int p = 0; p < 3; ++p) S += pms[(r * 3 + p) * 2 + 1] * __expf(pms[(r * 3 + p) * 2] - M);
    lse_out[r] = M + logf(S);

    int p0 = 0, p1 = 0, p2 = 0;
    for (int j = 0; j < 16; ++j) {
        float v0 = (p0 < 16) ? ptv[(r * 3 + 0) * 16 + p0] : -INFINITY;
        float v1 = (p1 < 16) ? ptv[(r * 3 + 1) * 16 + p1] : -INFINITY;
        float v2 = (p2 < 16) ? ptv[(r * 3 + 2) * 16 + p2] : -INFINITY;
        int i0 = (p0 < 16) ? pti[(r * 3 + 0) * 16 + p0] : 0x7fffffff;
        int i1 = (p1 < 16) ? pti[(r * 3 + 1) * 16 + p1] : 0x7fffffff;
        int i2 = (p2 < 16) ? pti[(r * 3 + 2) * 16 + p2] : 0x7fffffff;
        // pick best (value desc, index asc on ties)
        int sel = 0; float bv = v0; int bi = i0;
        if (v1 > bv || (v1 == bv && i1 < bi)) { sel = 1; bv = v1; bi = i1; }
        if (v2 > bv || (v2 == bv && i2 < bi)) { sel = 2; bv = v2; bi = i2; }
        tv_out[r * 16 + j] = bv; ti_out[r * 16 + j] = bi;
        if (sel == 0) p0++; else if (sel == 1) p1++; else p2++;
    }
}

// ---------------------------------------------------------------------------
// beam_logic: per batch b: merge 8x16 candidates -> top-16, beam bookkeeping.
// (unchanged from the verified R2 kernel)
// ---------------------------------------------------------------------------
__global__ __launch_bounds__(256) void beam_logic(
    const float* __restrict__ lse, const float* __restrict__ tv_in,
    const int* __restrict__ ti_in, const int* __restrict__ input_ids,
    const int* __restrict__ seq_state, const int* __restrict__ rss,
    const float* __restrict__ lps, const float* __restrict__ rlps,
    const int* __restrict__ isfin, const int* __restrict__ step_p,
    float* __restrict__ out, int* __restrict__ improve_ws)
{
    const int b = blockIdx.x;
    const int tid = threadIdx.x;

    __shared__ float redv[256]; __shared__ int redi[256];
    __shared__ float topv[16]; __shared__ int topflat[16];
    __shared__ float s_nlp[8], s_nrlp[8];
    __shared__ int s_mode, s_beam, s_sel_k, s_sel_v, s_step;

    float cv = -INFINITY; int ci = 0x7fffffff;
    if (tid < 128) {
        int k = tid >> 4, slot = tid & 15;
        int r = b * KK + k;
        cv = tv_in[r * 16 + slot] - lse[r] + rlps[b * KK + k];
        ci = k * VV + ti_in[r * 16 + slot];
    }
    for (int rs = 0; rs < 16; ++rs) {
        redv[tid] = cv; redi[tid] = ci;
        __syncthreads();
        for (int st = 128; st > 0; st >>= 1) {
            if (tid < st) {
                float v2 = redv[tid + st]; int i2 = redi[tid + st];
                if (v2 > redv[tid] || (v2 == redv[tid] && i2 < redi[tid])) {
                    redv[tid] = v2; redi[tid] = i2;
                }
            }
            __syncthreads();
        }
        float wv = redv[0]; int wi = redi[0];
        if (tid == 0) { topv[rs] = wv; topflat[rs] = wi; }
        __syncthreads();
        if (ci == wi) { cv = -INFINITY; ci = 0x7fffffff; }
    }

    if (tid == 0) {
        const int step = *step_p;
        s_step = step;
        const float stepf = (float)step;
        int tkk[16], tkid[16]; bool fin[16];
        float runtl[16], pen[16];
        for (int j = 0; j < 16; ++j) {
            int flat = topflat[j];
            tkk[j] = flat / VV; tkid[j] = flat % VV;
            fin[j] = (tkid[j] == EOS_TOK);
            runtl[j] = topv[j] + (fin[j] ? LNCf : 0.f);
            pen[j]   = topv[j] / stepf + (fin[j] ? 0.f : LNCf);
        }
        int ni[8]; unsigned used = 0;
        for (int i = 0; i < 8; ++i) {
            int best = -1;
            for (int j = 0; j < 16; ++j)
                if (!((used >> j) & 1) && (best < 0 || runtl[j] > runtl[best])) best = j;
            ni[i] = best; used |= 1u << best;
            s_nrlp[i] = runtl[best];
        }
        float merged[24];
        for (int j = 0; j < 8; ++j)  merged[j] = lps[b * KK + j];
        for (int j = 0; j < 16; ++j) merged[8 + j] = pen[j];
        int mi2[8]; unsigned used2 = 0; bool anyf = false;
        for (int i = 0; i < 8; ++i) {
            int best = -1;
            for (int j = 0; j < 24; ++j)
                if (!((used2 >> j) & 1) && (best < 0 || merged[j] > merged[best])) best = j;
            mi2[i] = best; used2 |= 1u << best;
            s_nlp[i] = merged[best];
            bool f = (best < 8) ? (isfin[b * KK + best] != 0) : fin[best - 8];
            anyf |= f;
        }
        float worst = LNCf;
        if (anyf) {
            worst = lps[b * KK];
            for (int j = 1; j < 8; ++j) worst = fminf(worst, lps[b * KK + j]);
        }
        improve_ws[b] = ((rlps[b * KK] / stepf) > worst) ? 1 : 0;
        if (anyf) {
            int m0i = mi2[0];
            if (m0i < 8) { s_mode = 0; s_beam = m0i; }
            else { s_mode = 1; s_sel_k = tkk[m0i - 8]; s_sel_v = tkid[m0i - 8]; }
        } else {
            int j0 = ni[0];
            s_mode = 1; s_sel_k = tkk[j0]; s_sel_v = tkid[j0];
        }
    }
    __syncthreads();

    if (tid < LL) {
        int tokv;
        if (s_mode == 0) {
            tokv = seq_state[(b * KK + s_beam) * LL + tid];
        } else {
            tokv = (tid == s_step) ? s_sel_v
                 : ((tid == 0) ? input_ids[b * KK + s_sel_k]
                               : rss[(b * KK + s_sel_k) * LL + tid]);
        }
        out[b * LL + tid] = (float)tokv;
    }
    if (tid < 8) {
        out[BB * LL + 1 + b * KK + tid] = s_nlp[tid];
        out[BB * LL + 1 + BB * KK + b * KK + tid] = s_nrlp[tid];
    }
}

// ---------------------------------------------------------------------------
__global__ __launch_bounds__(64) void finalize_done(
    const int* __restrict__ improve_ws, const int* __restrict__ step_p,
    float* __restrict__ out)
{
    int tid = threadIdx.x;
    bool imp = improve_ws[tid] != 0;
    bool any = __any(imp);
    if (tid == 0) {
        int step = *step_p;
        bool cont = (step < LL) && any;
        out[BB * LL] = cont ? 0.f : 1.f;
    }
}

// ---------------------------------------------------------------------------
extern "C" void kernel_launch(void* const* d_in, const int* in_sizes, int n_in,
                              void* d_out, int out_size, void* d_ws, size_t ws_size,
                              hipStream_t stream) {
    const int*   input_ids = (const int*)d_in[0];
    const int*   seq_state = (const int*)d_in[1];
    const int*   rss       = (const int*)d_in[2];
    const float* lps       = (const float*)d_in[3];
    const float* rlps      = (const float*)d_in[4];
    const int*   isfin     = (const int*)d_in[5];
    const float* embed     = (const float*)d_in[6];
    const float* W         = (const float*)d_in[7];
    const int*   step_p    = (const int*)d_in[8];
    float* out = (float*)d_out;

    // ws layout (~71 MB)
    char* ws = (char*)d_ws;
    size_t off = 0;
    auto alloc = [&](size_t bytes) { void* p = ws + off; off += (bytes + 255) & ~(size_t)255; return p; };
    ushort_t* Wt     = (ushort_t*)alloc((size_t)NSLICE * DD * 2);      // 34.3 MB
    float*    lslice = (float*)alloc((size_t)512 * NSLICE * 4);        // 34.3 MB
    ushort_t* At_hi  = (ushort_t*)alloc((size_t)512 * DD * 2);
    ushort_t* At_lo  = (ushort_t*)alloc((size_t)512 * DD * 2);
    float*    pms    = (float*)alloc((size_t)512 * 3 * 2 * 4);
    float*    ptv    = (float*)alloc((size_t)512 * 3 * 16 * 4);
    int*      pti    = (int*)alloc((size_t)512 * 3 * 16 * 4);
    float*    lse    = (float*)alloc(512 * 4);
    float*    tvals  = (float*)alloc(512 * 16 * 4);
    int*      tidx   = (int*)alloc(512 * 16 * 4);
    int*      improw = (int*)alloc(64 * 4);
    (void)ws_size; (void)in_sizes; (void)n_in; (void)out_size;

    conv_a<<<512, 256, 0, stream>>>(embed, input_ids, rss, step_p, At_hi, At_lo);
    for (int p = 0; p < 3; ++p) {
        conv_w<<<dim3(16, 262), 256, 0, stream>>>(W, Wt, p * NSLICE);
        gemm_pass<<<4 * NT_PASS, 256, 0, stream>>>(At_hi, At_lo, Wt, lslice);
        const int n_valid = (p == 2) ? (VV - 2 * NSLICE) : NSLICE;     // 16721 on last pass
        topk_partial<<<512, 256, 0, stream>>>(lslice, pms, ptv, pti, p, n_valid);
    }
    final_merge<<<512, 64, 0, stream>>>(pms, ptv, pti, lse, tvals, tidx);
    beam_logic<<<64, 256, 0, stream>>>(lse, tvals, tidx, input_ids, seq_state,
                                       rss, lps, rlps, isfin, step_p, out, improw);
    finalize_done<<<1, 64, 0, stream>>>(improw, step_p, out);
}

// Round 4
// 421.964 us; speedup vs baseline: 2.6938x; 1.0237x over previous
//
#include <hip/hip_runtime.h>
#include <cstdint>
#include <cstddef>

// Problem constants (fixed by the reference)
#define BB 64
#define KK 8
#define LL 256
#define VV 50257
#define DD 1024
#define EOS_TOK 50256
#define LNCf (-1000000000.0f)
#define NSLICE 16768            // per-pass n-width = 131 tiles * 128 (3*16768 = 50304 >= VV)
#define NT_PASS 131

typedef unsigned short ushort_t;
typedef __attribute__((ext_vector_type(4))) float f32x4;
typedef __attribute__((ext_vector_type(8))) short bf16x8;

// 4-byte-aligned float4 for loads at stride V=50257 (odd): rows not 16B aligned.
struct __attribute__((packed, aligned(4))) f4u { float x, y, z, w; };

// round-to-nearest-even f32 -> bf16 bits
__device__ inline ushort_t bf16_rne(float x) {
    unsigned u = __float_as_uint(x);
    return (ushort_t)((u + 0x7fffu + ((u >> 16) & 1u)) >> 16);
}
__device__ inline float bf16_f32(ushort_t b) { return __uint_as_float(((unsigned)b) << 16); }

// ---------------------------------------------------------------------------
// conv_a: gather token rows, split fp32 embed -> bf16 hi + bf16 lo.
// ---------------------------------------------------------------------------
__global__ __launch_bounds__(256) void conv_a(
    const float* __restrict__ embed, const int* __restrict__ input_ids,
    const int* __restrict__ rss, const int* __restrict__ step_p,
    ushort_t* __restrict__ At_hi, ushort_t* __restrict__ At_lo)
{
    const int r = blockIdx.x;
    const int t = threadIdx.x;
    const int step = *step_p;
    const int tok = (step == 1) ? input_ids[r] : rss[r * LL + (step - 1)];
    f32x4 v = *(const f32x4*)(embed + (size_t)tok * DD + t * 4);
    ushort4 h, l;
    h.x = bf16_rne(v[0]); l.x = bf16_rne(v[0] - bf16_f32(h.x));
    h.y = bf16_rne(v[1]); l.y = bf16_rne(v[1] - bf16_f32(h.y));
    h.z = bf16_rne(v[2]); l.z = bf16_rne(v[2] - bf16_f32(h.z));
    h.w = bf16_rne(v[3]); l.w = bf16_rne(v[3] - bf16_f32(h.w));
    *(ushort4*)(At_hi + (size_t)r * DD + t * 4) = h;
    *(ushort4*)(At_lo + (size_t)r * DD + t * 4) = l;
}

// ---------------------------------------------------------------------------
// conv_w: transpose+convert one n-slice of W: W[k][n] f32 -> Wt[n_local][k] bf16.
// ---------------------------------------------------------------------------
__global__ __launch_bounds__(256) void conv_w(
    const float* __restrict__ W, ushort_t* __restrict__ Wt, int nglob_base)
{
    __shared__ ushort_t tile[64][66];
    const int t = threadIdx.x;
    const int k0 = blockIdx.x * 64;
    const int nloc0 = blockIdx.y * 64;
    const int n0 = nglob_base + nloc0;
    const int kr = t >> 4;           // 0..15
    const int nc = (t & 15) * 4;     // 0..60
#pragma unroll
    for (int j = 0; j < 4; ++j) {
        const int k = k0 + kr + j * 16;
        const int n = n0 + nc;
        const float* wp = W + (size_t)k * VV + n;
        float a, b2, c, d;
        if (n + 3 < VV) { f4u u = *(const f4u*)wp; a = u.x; b2 = u.y; c = u.z; d = u.w; }
        else {
            a  = (n     < VV) ? wp[0] : 0.f;
            b2 = (n + 1 < VV) ? wp[1] : 0.f;
            c  = (n + 2 < VV) ? wp[2] : 0.f;
            d  = (n + 3 < VV) ? wp[3] : 0.f;
        }
        tile[kr + j * 16][nc + 0] = bf16_rne(a);
        tile[kr + j * 16][nc + 1] = bf16_rne(b2);
        tile[kr + j * 16][nc + 2] = bf16_rne(c);
        tile[kr + j * 16][nc + 3] = bf16_rne(d);
    }
    __syncthreads();
    const int nr = t >> 2;           // 0..63
    const int kc = (t & 3) * 16;     // 0,16,32,48
    ushort_t vals[16];
#pragma unroll
    for (int j = 0; j < 16; ++j) vals[j] = tile[kc + j][nr];
    uint4 u0, u1;
    u0.x = vals[0] | ((unsigned)vals[1] << 16);  u0.y = vals[2] | ((unsigned)vals[3] << 16);
    u0.z = vals[4] | ((unsigned)vals[5] << 16);  u0.w = vals[6] | ((unsigned)vals[7] << 16);
    u1.x = vals[8] | ((unsigned)vals[9] << 16);  u1.y = vals[10] | ((unsigned)vals[11] << 16);
    u1.z = vals[12] | ((unsigned)vals[13] << 16); u1.w = vals[14] | ((unsigned)vals[15] << 16);
    ushort_t* op = Wt + (size_t)(nloc0 + nr) * DD + k0 + kc;
    *(uint4*)op = u0;
    *(uint4*)(op + 8) = u1;
}

// ---------------------------------------------------------------------------
// gemm_pass: logits_slice[512][16768] f32 = (Ahi+Alo)[512][1024] @ Wt^T (bf16)
// (unchanged verified m97-style structure)
// ---------------------------------------------------------------------------
__global__ __launch_bounds__(256) void gemm_pass(
    const ushort_t* __restrict__ At_hi, const ushort_t* __restrict__ At_lo,
    const ushort_t* __restrict__ Wt, float* __restrict__ logits)
{
    __shared__ ushort_t smem[24576];          // 48 KB: Ahi | Alo | Bs (16 KB each)
    ushort_t* Ah = smem;
    ushort_t* Al = smem + 8192;
    ushort_t* Bs = smem + 16384;

    const int tid = threadIdx.x;
    const int wave = tid >> 6;
    const int lane = tid & 63;
    const int m_t = blockIdx.x & 3;
    const int n_t = blockIdx.x >> 2;          // 0..130
    const int m0 = m_t * 128;
    const int wm = wave >> 1, wn = wave & 1;
    const int fr = lane & 15;
    const int q  = lane >> 4;

    const int srow = lane >> 3;               // 0..7
    const int schunk = lane & 7;              // 0..7

    f32x4 acc[4][4];
#pragma unroll
    for (int i = 0; i < 4; ++i)
#pragma unroll
        for (int j = 0; j < 4; ++j)
#pragma unroll
            for (int e = 0; e < 4; ++e) acc[i][j][e] = 0.f;

    for (int t7 = 0; t7 < 16; ++t7) {
        const int kb = t7 * 64;
#pragma unroll
        for (int i = 0; i < 4; ++i) {
            const int row = (i * 4 + wave) * 8 + srow;
            const int soff = (schunk ^ (row & 7)) * 8;
            const ushort_t* srcH = At_hi + (size_t)(m0 + row) * DD + kb + soff;
            const ushort_t* srcL = At_lo + (size_t)(m0 + row) * DD + kb + soff;
            const ushort_t* srcB = Wt + (size_t)(n_t * 128 + row) * DD + kb + soff;
            __builtin_amdgcn_global_load_lds(
                (const __attribute__((address_space(1))) unsigned int*)srcH,
                (__attribute__((address_space(3))) unsigned int*)(Ah + (i * 4 + wave) * 512),
                16, 0, 0);
            __builtin_amdgcn_global_load_lds(
                (const __attribute__((address_space(1))) unsigned int*)srcL,
                (__attribute__((address_space(3))) unsigned int*)(Al + (i * 4 + wave) * 512),
                16, 0, 0);
            __builtin_amdgcn_global_load_lds(
                (const __attribute__((address_space(1))) unsigned int*)srcB,
                (__attribute__((address_space(3))) unsigned int*)(Bs + (i * 4 + wave) * 512),
                16, 0, 0);
        }
        __syncthreads();
#pragma unroll
        for (int h = 0; h < 2; ++h) {
            bf16x8 b[4];
#pragma unroll
            for (int fn = 0; fn < 4; ++fn) {
                const int row = wn * 64 + fn * 16 + fr;
                const int off = ((h * 4 + q) ^ (row & 7)) * 16;
                b[fn] = *(const bf16x8*)((const char*)(Bs + row * 64) + off);
            }
#pragma unroll
            for (int fm = 0; fm < 4; ++fm) {
                const int row = wm * 64 + fm * 16 + fr;
                const int off = ((h * 4 + q) ^ (row & 7)) * 16;
                bf16x8 ah = *(const bf16x8*)((const char*)(Ah + row * 64) + off);
                bf16x8 al = *(const bf16x8*)((const char*)(Al + row * 64) + off);
#pragma unroll
                for (int fn = 0; fn < 4; ++fn) {
                    acc[fm][fn] = __builtin_amdgcn_mfma_f32_16x16x32_bf16(ah, b[fn], acc[fm][fn], 0, 0, 0);
                    acc[fm][fn] = __builtin_amdgcn_mfma_f32_16x16x32_bf16(al, b[fn], acc[fm][fn], 0, 0, 0);
                }
            }
        }
        __syncthreads();
    }

    const int crow0 = m0 + wm * 64 + q * 4;
    const int ccol0 = n_t * 128 + wn * 64 + fr;
#pragma unroll
    for (int fm = 0; fm < 4; ++fm)
#pragma unroll
        for (int fn = 0; fn < 4; ++fn) {
            const int col = ccol0 + fn * 16;
#pragma unroll
            for (int e = 0; e < 4; ++e)
                logits[(size_t)(crow0 + fm * 16 + e) * NSLICE + col] = acc[fm][fn][e];
        }
}

// ---------------------------------------------------------------------------
// topk_partial: per row r (512): online (max, sumexp) + top-16 over one
// 16768-col f32 slice. Wave-shfl LSE reduce; merge tree with only 2 barriers
// (levels <=64 run wave-0-only, wave-synchronous).
// ---------------------------------------------------------------------------
__global__ __launch_bounds__(256) void topk_partial(
    const float* __restrict__ lslice, float* __restrict__ pms,
    float* __restrict__ ptv, int* __restrict__ pti,
    int pass, int n_valid)
{
    const int r = blockIdx.x;
    const int tid = threadIdx.x;
    const float* rowp = lslice + (size_t)r * NSLICE;
    const int gbase = pass * NSLICE;

    float m = -INFINITY, s = 0.f;
    float v[16]; int id[16];
#pragma unroll
    for (int j = 0; j < 16; ++j) { v[j] = -INFINITY; id[j] = 0x7fffffff; }

    auto ins = [&](float x, int c) {
        if (x > v[15]) {
            float cv = x; int ci = c;
#pragma unroll
            for (int j = 0; j < 16; ++j) {
                bool sw = (cv > v[j]);
                float tf = v[j]; int ti2 = id[j];
                if (sw) { v[j] = cv; id[j] = ci; cv = tf; ci = ti2; }
            }
        }
    };

    for (int i = 0; i < 17; ++i) {
        const int c4 = i * 256 + tid;
        if (c4 >= NSLICE / 4) break;
        const int col = c4 * 4;
        f32x4 x = *(const f32x4*)(rowp + col);
        if (col + 3 >= n_valid) {
            if (col + 0 >= n_valid) x[0] = -INFINITY;
            if (col + 1 >= n_valid) x[1] = -INFINITY;
            if (col + 2 >= n_valid) x[2] = -INFINITY;
            if (col + 3 >= n_valid) x[3] = -INFINITY;
        }
        const float m4 = fmaxf(fmaxf(x[0], x[1]), fmaxf(x[2], x[3]));
        const float mn = fmaxf(m, m4);
        s = s * __expf(m - mn) + __expf(x[0] - mn) + __expf(x[1] - mn)
            + __expf(x[2] - mn) + __expf(x[3] - mn);
        m = mn;
        if (m4 > v[15]) { ins(x[0], col); ins(x[1], col + 1); ins(x[2], col + 2); ins(x[3], col + 3); }
    }

    // wave-level (m,s) reduce via shfl (no barriers)
#pragma unroll
    for (int sh = 1; sh < 64; sh <<= 1) {
        float m2 = __shfl_xor(m, sh, 64);
        float s2 = __shfl_xor(s, sh, 64);
        float mm = fmaxf(m, m2);
        s = s * __expf(m - mm) + s2 * __expf(m2 - mm);
        m = mm;
    }
    __shared__ float wm4[4], ws4[4];
    if ((tid & 63) == 0) { wm4[tid >> 6] = m; ws4[tid >> 6] = s; }

    // merge tree: store lists, then 8 levels with only 2 barriers
    __shared__ float mvv[256][17];
    __shared__ int mii[256][17];
#pragma unroll
    for (int j = 0; j < 16; ++j) { mvv[tid][j] = v[j]; mii[tid][j] = id[j]; }
    __syncthreads();

    if (tid == 0) {
        float M = fmaxf(fmaxf(wm4[0], wm4[1]), fmaxf(wm4[2], wm4[3]));
        float S = ws4[0] * __expf(wm4[0] - M) + ws4[1] * __expf(wm4[1] - M)
                + ws4[2] * __expf(wm4[2] - M) + ws4[3] * __expf(wm4[3] - M);
        pms[(r * 3 + pass) * 2] = M;
        pms[(r * 3 + pass) * 2 + 1] = S;
    }

    auto level = [&](int st) {
        float nv[16]; int ni2[16];
        const float* av = mvv[tid];      const int* ai = mii[tid];
        const float* bv = mvv[tid + st]; const int* bi = mii[tid + st];
        int pa = 0, pb = 0;
#pragma unroll
        for (int o = 0; o < 16; ++o) {
            float va = av[pa], vb = bv[pb];
            int ia = ai[pa], ib = bi[pb];
            bool ta = (va > vb) || (va == vb && ia < ib);
            nv[o] = ta ? va : vb;
            ni2[o] = ta ? ia : ib;
            pa += ta ? 1 : 0;
            pb += ta ? 0 : 1;
        }
#pragma unroll
        for (int j = 0; j < 16; ++j) { mvv[tid][j] = nv[j]; mii[tid][j] = ni2[j]; }
    };

    if (tid < 128) level(128);
    __syncthreads();
    if (tid < 64) {              // wave 0 only: lockstep, reads precede writes
        level(64); level(32); level(16); level(8); level(4); level(2); level(1);
        if (tid < 16) {
            ptv[(r * 3 + pass) * 16 + tid] = mvv[0][tid];
            pti[(r * 3 + pass) * 16 + tid] = gbase + mii[0][tid];
        }
    }
}

// ---------------------------------------------------------------------------
// beam_logic: one wave per batch, barrier-free. Candidates = 8 rows x 48
// per-pass partials (union of pass-top-16 is a superset of row-top-16).
// 16 extraction rounds via shfl_xor butterfly; lane 0 does bookkeeping.
// ---------------------------------------------------------------------------
__global__ __launch_bounds__(64) void beam_logic(
    const float* __restrict__ pms, const float* __restrict__ ptv,
    const int* __restrict__ pti, const int* __restrict__ input_ids,
    const int* __restrict__ seq_state, const int* __restrict__ rss,
    const float* __restrict__ lps, const float* __restrict__ rlps,
    const int* __restrict__ isfin, const int* __restrict__ step_p,
    float* __restrict__ out, int* __restrict__ improve_ws)
{
    const int b = blockIdx.x;
    const int lane = threadIdx.x;
    const int kk = lane >> 3;                 // beam row 0..7 for this lane
    const int r = b * KK + kk;

    // per-row lse from the 3 (m,s) partials (every lane computes its row's)
    float M = fmaxf(fmaxf(pms[(r * 3 + 0) * 2], pms[(r * 3 + 1) * 2]), pms[(r * 3 + 2) * 2]);
    float S = 0.f;
#pragma unroll
    for (int p = 0; p < 3; ++p) S += pms[(r * 3 + p) * 2 + 1] * __expf(pms[(r * 3 + p) * 2] - M);
    const float off_r = rlps[r] - (M + logf(S));

    // 6 candidates per lane (8 lanes per row x 6 = 48 slots)
    const int s0 = (lane & 7) * 6;
    float cv[6]; int cidx[6];
#pragma unroll
    for (int mq = 0; mq < 6; ++mq) {
        const int sl = s0 + mq, p = sl >> 4, j = sl & 15;
        cv[mq] = ptv[(r * 3 + p) * 16 + j] + off_r;
        cidx[mq] = kk * VV + pti[(r * 3 + p) * 16 + j];
    }

    // 16 extraction rounds (value desc, flat index asc on ties)
    float wv[16]; int wi[16];
#pragma unroll
    for (int t = 0; t < 16; ++t) {
        float bv = cv[0]; int bi = cidx[0];
#pragma unroll
        for (int mq = 1; mq < 6; ++mq)
            if (cv[mq] > bv || (cv[mq] == bv && cidx[mq] < bi)) { bv = cv[mq]; bi = cidx[mq]; }
#pragma unroll
        for (int sh = 1; sh < 64; sh <<= 1) {
            float v2 = __shfl_xor(bv, sh, 64);
            int i2 = __shfl_xor(bi, sh, 64);
            if (v2 > bv || (v2 == bv && i2 < bi)) { bv = v2; bi = i2; }
        }
        wv[t] = bv; wi[t] = bi;
#pragma unroll
        for (int mq = 0; mq < 6; ++mq)
            if (cidx[mq] == bi) { cv[mq] = -INFINITY; cidx[mq] = 0x7fffffff; }
    }

    // lane 0: bookkeeping, fully unrolled (compile-time indices -> registers)
    int mode = 0, beam = 0, selk = 0, selv = 0, step = 0;
    if (lane == 0) {
        step = *step_p;
        const float stepf = (float)step;
        float runtl[16]; int tkk[16], tkid[16]; unsigned finmask = 0;
#pragma unroll
        for (int j = 0; j < 16; ++j) {
            tkk[j] = wi[j] / VV;
            tkid[j] = wi[j] - tkk[j] * VV;
            const bool f = (tkid[j] == EOS_TOK);
            finmask |= (f ? 1u : 0u) << j;
            runtl[j] = wv[j] + (f ? LNCf : 0.f);
        }
        // top-8 of runtl (stable: strict >, ascending scan)
        unsigned used = 0;
        int selk_run = 0, selv_run = 0;
#pragma unroll
        for (int i = 0; i < 8; ++i) {
            float bvv = 0.f; int bj = -1, bk = 0, bv2 = 0;
#pragma unroll
            for (int j = 0; j < 16; ++j) {
                if (!((used >> j) & 1u) && (bj < 0 || runtl[j] > bvv)) {
                    bvv = runtl[j]; bj = j; bk = tkk[j]; bv2 = tkid[j];
                }
            }
            used |= 1u << bj;
            out[BB * LL + 1 + BB * KK + b * KK + i] = bvv;   // next_running_log_probs
            if (i == 0) { selk_run = bk; selv_run = bv2; }
        }
        // merged top-8 of [lps(8) ++ penalized(16)]
        float mvx[24]; unsigned mfinmask = 0;
#pragma unroll
        for (int j = 0; j < 8; ++j) {
            mvx[j] = lps[b * KK + j];
            mfinmask |= ((isfin[b * KK + j] != 0) ? 1u : 0u) << j;
        }
#pragma unroll
        for (int j = 0; j < 16; ++j) {
            const bool f = (finmask >> j) & 1u;
            mvx[8 + j] = wv[j] / stepf + (f ? 0.f : LNCf);
            mfinmask |= (f ? 1u : 0u) << (8 + j);
        }
        unsigned used2 = 0; int anyf = 0;
        int m0_state = 0, m0_beam = 0, m0_k = 0, m0_v = 0;
#pragma unroll
        for (int i = 0; i < 8; ++i) {
            float bvv = 0.f; int bj = -1, bf = 0, bstate = 0, bbeam = 0, bk = 0, bv2 = 0;
#pragma unroll
            for (int j = 0; j < 24; ++j) {
                if (!((used2 >> j) & 1u) && (bj < 0 || mvx[j] > bvv)) {
                    bvv = mvx[j]; bj = j; bf = (mfinmask >> j) & 1u;
                    bstate = (j < 8) ? 1 : 0; bbeam = j;
                    bk = (j < 8) ? 0 : tkk[j - 8]; bv2 = (j < 8) ? 0 : tkid[j - 8];
                }
            }
            used2 |= 1u << bj;
            out[BB * LL + 1 + b * KK + i] = bvv;             // next_log_probs
            anyf |= bf;
            if (i == 0) { m0_state = bstate; m0_beam = bbeam; m0_k = bk; m0_v = bv2; }
        }
        float worst = LNCf;
        if (anyf) {
            worst = lps[b * KK];
#pragma unroll
            for (int j = 1; j < 8; ++j) worst = fminf(worst, lps[b * KK + j]);
        }
        improve_ws[b] = ((rlps[b * KK] / stepf) > worst) ? 1 : 0;
        if (anyf) {
            if (m0_state) { mode = 0; beam = m0_beam; }
            else { mode = 1; selk = m0_k; selv = m0_v; }
        } else {
            mode = 1; selk = selk_run; selv = selv_run;
        }
    }
    // broadcast selection to all lanes
    mode = __shfl(mode, 0, 64);
    beam = __shfl(beam, 0, 64);
    selk = __shfl(selk, 0, 64);
    selv = __shfl(selv, 0, 64);
    step = __shfl(step, 0, 64);

    // write generated token row (256 tokens, 4 per lane)
#pragma unroll
    for (int it = 0; it < 4; ++it) {
        const int t2 = it * 64 + lane;
        int tokv;
        if (mode == 0) {
            tokv = seq_state[(b * KK + beam) * LL + t2];
        } else {
            tokv = (t2 == step) ? selv
                 : ((t2 == 0) ? input_ids[b * KK + selk]
                              : rss[(b * KK + selk) * LL + t2]);
        }
        out[b * LL + t2] = (float)tokv;
    }
}

// ---------------------------------------------------------------------------
__global__ __launch_bounds__(64) void finalize_done(
    const int* __restrict__ improve_ws, const int* __restrict__ step_p,
    float* __restrict__ out)
{
    int tid = threadIdx.x;
    bool imp = improve_ws[tid] != 0;
    bool any = __any(imp);
    if (tid == 0) {
        int step = *step_p;
        bool cont = (step < LL) && any;
        out[BB * LL] = cont ? 0.f : 1.f;
    }
}

// ---------------------------------------------------------------------------
extern "C" void kernel_launch(void* const* d_in, const int* in_sizes, int n_in,
                              void* d_out, int out_size, void* d_ws, size_t ws_size,
                              hipStream_t stream) {
    const int*   input_ids = (const int*)d_in[0];
    const int*   seq_state = (const int*)d_in[1];
    const int*   rss       = (const int*)d_in[2];
    const float* lps       = (const float*)d_in[3];
    const float* rlps      = (const float*)d_in[4];
    const int*   isfin     = (const int*)d_in[5];
    const float* embed     = (const float*)d_in[6];
    const float* W         = (const float*)d_in[7];
    const int*   step_p    = (const int*)d_in[8];
    float* out = (float*)d_out;

    // ws layout (~71 MB)
    char* ws = (char*)d_ws;
    size_t off = 0;
    auto alloc = [&](size_t bytes) { void* p = ws + off; off += (bytes + 255) & ~(size_t)255; return p; };
    ushort_t* Wt     = (ushort_t*)alloc((size_t)NSLICE * DD * 2);      // 34.3 MB
    float*    lslice = (float*)alloc((size_t)512 * NSLICE * 4);        // 34.3 MB
    ushort_t* At_hi  = (ushort_t*)alloc((size_t)512 * DD * 2);
    ushort_t* At_lo  = (ushort_t*)alloc((size_t)512 * DD * 2);
    float*    pms    = (float*)alloc((size_t)512 * 3 * 2 * 4);
    float*    ptv    = (float*)alloc((size_t)512 * 3 * 16 * 4);
    int*      pti    = (int*)alloc((size_t)512 * 3 * 16 * 4);
    int*      improw = (int*)alloc(64 * 4);
    (void)ws_size; (void)in_sizes; (void)n_in; (void)out_size;

    conv_a<<<512, 256, 0, stream>>>(embed, input_ids, rss, step_p, At_hi, At_lo);
    for (int p = 0; p < 3; ++p) {
        conv_w<<<dim3(16, 262), 256, 0, stream>>>(W, Wt, p * NSLICE);
        gemm_pass<<<4 * NT_PASS, 256, 0, stream>>>(At_hi, At_lo, Wt, lslice);
        const int n_valid = (p == 2) ? (VV - 2 * NSLICE) : NSLICE;     // 16721 on last pass
        topk_partial<<<512, 256, 0, stream>>>(lslice, pms, ptv, pti, p, n_valid);
    }
    beam_logic<<<64, 64, 0, stream>>>(pms, ptv, pti, input_ids, seq_state,
                                      rss, lps, rlps, isfin, step_p, out, improw);
    finalize_done<<<1, 64, 0, stream>>>(improw, step_p, out);
}